// Round 6
// baseline (179.336 us; speedup 1.0000x reference)
//
#include <hip/hip_runtime.h>
#include <hip/hip_bf16.h>

#define NCH      256
#define NNB      262144
#define BN       64
#define NTILES   (NNB / BN)   // 4096
#define NB       256          // K1 grid: 1 block per CU
#define ITPB     (NTILES / NB) // 16 tiles per block
#define NENT     (NCH * 6)

typedef __bf16        bf16x8 __attribute__((ext_vector_type(8)));
typedef float         f32x4  __attribute__((ext_vector_type(4)));
typedef unsigned int  u32x4  __attribute__((ext_vector_type(4)));
typedef unsigned int  u32x2  __attribute__((ext_vector_type(2)));
typedef short         v4s    __attribute__((ext_vector_type(4)));

union FragU  { u32x4 u; bf16x8 b; };
union Frag2U { u32x2 u; v4s    s; };

__device__ __forceinline__ unsigned pk2(float lo, float hi) {
    union { __hip_bfloat162 h2; unsigned u; } cv;
    cv.h2 = __float22bfloat162_rn(make_float2(lo, hi));
    return cv.u;
}

__device__ __forceinline__ const float* uni_ptr(const float* p) {
    unsigned long long u = (unsigned long long)p;
    unsigned lo = __builtin_amdgcn_readfirstlane((unsigned)u);
    unsigned hi = __builtin_amdgcn_readfirstlane((unsigned)(u >> 32));
    return (const float*)(((unsigned long long)hi << 32) | lo);
}

// raw barrier: LDS writes visible, global loads stay in flight (no vmcnt drain)
#define LBAR() do {                                                  \
    asm volatile("s_waitcnt lgkmcnt(0)" ::: "memory");               \
    __builtin_amdgcn_sched_barrier(0);                               \
    __builtin_amdgcn_s_barrier();                                    \
    __builtin_amdgcn_sched_barrier(0);                               \
} while (0)

// One iteration: compute tile from buf P; prepare tile+NB into buf P^1.
// Wave (g = wave&1, kg = wave>>1): k in [kg*32,+32), cols [g*32,+32).
#define ITER(P, CUR, NXT, TILE_EXPR)                                               \
{                                                                                  \
    const int tile = (TILE_EXPR);                                                  \
    const int tn1  = tile + NB;                                                    \
    const int tn2  = tile + 2 * NB;                                                \
    {   /* issue rp(tn2) -> NXT (consumed next iteration's A) */                   \
        const int lt = (tn2 < NTILES) ? tn2 : tile;                                \
        const unsigned ii = (unsigned)(lt * BN) + (unsigned)c;                     \
        NXT[0] = rp[ii];                                                           \
        NXT[1] = rp[(size_t)NNB + ii];                                             \
        NXT[2] = rp[2 * (size_t)NNB + ii];                                         \
    }                                                                              \
    __builtin_amdgcn_sched_barrier(0);                                             \
    /* ---- B: compute from htile[P], dtab[P], gT[P] ---- */                       \
    _Pragma("unroll")                                                              \
    for (int cb = 0; cb < 2; ++cb) {                                               \
        const int colb = g * 32 + cb * 16;                                         \
        Frag2U gf;                                                                 \
        gf.u = *(const u32x2*)((const char*)gT[P] +                                \
               (((unsigned)(il * 128 + (colb + q * 4) * 2)) ^                      \
                (((unsigned)(il & 7)) << 3)));                                     \
        f32x4 hp0 = {0.f, 0.f, 0.f, 0.f}, hp1 = {0.f, 0.f, 0.f, 0.f};              \
        const unsigned rb = (unsigned)((colb + il) * 512);                         \
        const unsigned sw = ((unsigned)(il & 7)) << 4;                             \
        _Pragma("unroll")                                                          \
        for (int jb = 0; jb < 8; ++jb) {                                           \
            FragU f0;                                                              \
            f0.u = *(const u32x4*)((const char*)htile[P] +                         \
                   ((rb + (unsigned)(jb * 64 + q * 16)) ^ sw));                    \
            hp0 = __builtin_amdgcn_mfma_f32_16x16x32_bf16(f0.b, wf[0][jb].b, hp0, 0, 0, 0); \
            hp1 = __builtin_amdgcn_mfma_f32_16x16x32_bf16(f0.b, wf[1][jb].b, hp1, 0, 0, 0); \
        }                                                                          \
        f32x4 d4 = *(const f32x4*)&dtab[P][0][colb + q * 4];                       \
        f32x4 i4 = *(const f32x4*)&dtab[P][1][colb + q * 4];                       \
        Frag2U a0, a1;                                                             \
        {                                                                          \
            float m0 = __sinf(fk0 * d4[0]) * i4[0] * hp0[0];                       \
            float m1 = __sinf(fk0 * d4[1]) * i4[1] * hp0[1];                       \
            float m2 = __sinf(fk0 * d4[2]) * i4[2] * hp0[2];                       \
            float m3 = __sinf(fk0 * d4[3]) * i4[3] * hp0[3];                       \
            a0.u[0] = pk2(m0, m1); a0.u[1] = pk2(m2, m3);                          \
            float n0 = __sinf(fk1 * d4[0]) * i4[0] * hp1[0];                       \
            float n1 = __sinf(fk1 * d4[1]) * i4[1] * hp1[1];                       \
            float n2 = __sinf(fk1 * d4[2]) * i4[2] * hp1[2];                       \
            float n3 = __sinf(fk1 * d4[3]) * i4[3] * hp1[3];                       \
            a1.u[0] = pk2(n0, n1); a1.u[1] = pk2(n2, n3);                          \
        }                                                                          \
        acc0 = __builtin_amdgcn_mfma_f32_16x16x16bf16_1k(a0.s, gf.s, acc0, 0, 0, 0); \
        acc1 = __builtin_amdgcn_mfma_f32_16x16x16bf16_1k(a1.s, gf.s, acc1, 0, 0, 0); \
    }                                                                              \
    __builtin_amdgcn_sched_barrier(0);                                             \
    /* ---- A: prep tile tn1 into buf P^1 (vmcnt waits land here) ---- */          \
    if (tn1 < NTILES) {                                                            \
        u32x4 w0, w1;                                                              \
        w0[0] = pk2(hv[0], hv[1]);   w0[1] = pk2(hv[2], hv[3]);                    \
        w0[2] = pk2(hv[4], hv[5]);   w0[3] = pk2(hv[6], hv[7]);                    \
        w1[0] = pk2(hv[8], hv[9]);   w1[1] = pk2(hv[10], hv[11]);                  \
        w1[2] = pk2(hv[12], hv[13]); w1[3] = pk2(hv[14], hv[15]);                  \
        const unsigned swc = ((unsigned)(c & 7)) << 4;                             \
        *(u32x4*)((char*)htile[(P) ^ 1] +                                          \
                  (((unsigned)(c * 512 + wave * 32)) ^ swc)) = w0;                 \
        *(u32x4*)((char*)htile[(P) ^ 1] +                                          \
                  (((unsigned)(c * 512 + wave * 32 + 16)) ^ swc)) = w1;            \
        float dd = sqrtf(CUR[0] * CUR[0] + CUR[1] * CUR[1] + CUR[2] * CUR[2]);     \
        float iv = 1.0f / dd;                                                      \
        if (t < 64) {                                                              \
            dtab[(P) ^ 1][0][c] = dd;                                              \
            dtab[(P) ^ 1][1][c] = iv;                                              \
            float i2 = iv * iv;                                                    \
            float gg[6] = { CUR[0] * CUR[0] * i2, CUR[0] * CUR[1] * i2,            \
                            CUR[0] * CUR[2] * i2, CUR[1] * CUR[1] * i2,            \
                            CUR[1] * CUR[2] * i2, CUR[2] * CUR[2] * i2 };          \
            _Pragma("unroll")                                                      \
            for (int de = 0; de < 6; ++de) {                                       \
                unsigned off = ((unsigned)(de * 128 + c * 2)) ^                    \
                               (((unsigned)de) << 3);                              \
                *(unsigned short*)((char*)gT[(P) ^ 1] + off) =                     \
                    (unsigned short)(pk2(gg[de], 0.f) & 0xffffu);                  \
            }                                                                      \
        }                                                                          \
        const int lt2 = (tn2 < NTILES) ? tn2 : tile;                               \
        const unsigned ii2 = (unsigned)(lt2 * BN) + (unsigned)c;                   \
        _Pragma("unroll")                                                          \
        for (int j = 0; j < 16; ++j) hv[j] = hwb[(size_t)j * NNB + ii2];           \
    }                                                                              \
    LBAR();                                                                        \
}

// K1: 1024 threads = 16 waves; wave (g,kg) owns k [kg*32,+32) x cols [g*32,+32).
// GEMM1 (swapped): hp[col][k] via mfma(h_frag, wf[kt]); GEMM2: A[k][de] via 16x16x16.
// ws layout: [block][entry = k*6 + m6]
__global__ __launch_bounds__(1024, 1) void create_As_k1(
        const float* __restrict__ h, const float* __restrict__ rp,
        const float* __restrict__ W, float* __restrict__ ws)
{
    __shared__ unsigned short htile[2][BN * NCH];        // 2 x 32 KB [col][j], ^((c&7)<<4)
    __shared__ unsigned short gT[2][16 * BN];            // 2 x 2 KB [de][col], ^((de&7)<<3)
    __shared__ __align__(16) float dtab[2][2][BN];       // [p][{d,invd}][col]
    __shared__ float ared[NCH][8];                       // epilogue cross-half reduce, 8 KB

    const int t    = threadIdx.x;
    const int wave = t >> 6;        // 0..15
    const int il   = t & 15;
    const int q    = (t >> 4) & 3;
    const int c    = t & 63;
    const int g    = wave & 1;      // column half
    const int kg   = wave >> 1;     // k group of 32
    const float fk0 = (float)(kg * 32 + il + 1);
    const float fk1 = fk0 + 16.0f;

    ((unsigned*)gT)[t] = 0u;        // 1024 u32 == sizeof(gT)/4: rows 6..15 stay zero

    // W fragments: lane holds W[kg*32 + kt*16 + il][jb*32 + q*8 + e]  (64 VGPR)
    FragU wf[2][8];
    #pragma unroll
    for (int kt = 0; kt < 2; ++kt) {
        const float* wr = W + (size_t)(kg * 32 + kt * 16 + il) * NCH + q * 8;
        #pragma unroll
        for (int jb = 0; jb < 8; ++jb) {
            f32x4 a = *(const f32x4*)(wr + jb * 32);
            f32x4 b = *(const f32x4*)(wr + jb * 32 + 4);
            wf[kt][jb].u[0] = pk2(a[0], a[1]);
            wf[kt][jb].u[1] = pk2(a[2], a[3]);
            wf[kt][jb].u[2] = pk2(b[0], b[1]);
            wf[kt][jb].u[3] = pk2(b[2], b[3]);
        }
    }

    f32x4 acc0 = {0.f, 0.f, 0.f, 0.f};
    f32x4 acc1 = {0.f, 0.f, 0.f, 0.f};

    const float* hwb = uni_ptr(h + (size_t)(wave * 16) * NNB);  // staging rows, by wave id

    float hv[16];
    float pA[3], pB[3];

    const int tile0 = blockIdx.x;

    __syncthreads();   // gT zero-init + wf reads done before prologue LDS writes

    // -------- prologue: stage tile0 into buf 0; issue tile1 loads --------
    {
        const unsigned ii = (unsigned)(tile0 * BN) + (unsigned)c;
        pB[0] = rp[ii]; pB[1] = rp[(size_t)NNB + ii]; pB[2] = rp[2 * (size_t)NNB + ii];
        #pragma unroll
        for (int j = 0; j < 16; ++j) hv[j] = hwb[(size_t)j * NNB + ii];

        u32x4 w0, w1;
        w0[0] = pk2(hv[0], hv[1]);   w0[1] = pk2(hv[2], hv[3]);
        w0[2] = pk2(hv[4], hv[5]);   w0[3] = pk2(hv[6], hv[7]);
        w1[0] = pk2(hv[8], hv[9]);   w1[1] = pk2(hv[10], hv[11]);
        w1[2] = pk2(hv[12], hv[13]); w1[3] = pk2(hv[14], hv[15]);
        const unsigned swc = ((unsigned)(c & 7)) << 4;
        *(u32x4*)((char*)htile[0] + (((unsigned)(c * 512 + wave * 32)) ^ swc)) = w0;
        *(u32x4*)((char*)htile[0] + (((unsigned)(c * 512 + wave * 32 + 16)) ^ swc)) = w1;

        float dd = sqrtf(pB[0] * pB[0] + pB[1] * pB[1] + pB[2] * pB[2]);
        float iv = 1.0f / dd;
        if (t < 64) {
            dtab[0][0][c] = dd; dtab[0][1][c] = iv;
            float i2 = iv * iv;
            float gg[6] = { pB[0] * pB[0] * i2, pB[0] * pB[1] * i2, pB[0] * pB[2] * i2,
                            pB[1] * pB[1] * i2, pB[1] * pB[2] * i2, pB[2] * pB[2] * i2 };
            #pragma unroll
            for (int de = 0; de < 6; ++de) {
                unsigned off = ((unsigned)(de * 128 + c * 2)) ^ (((unsigned)de) << 3);
                *(unsigned short*)((char*)gT[0] + off) =
                    (unsigned short)(pk2(gg[de], 0.f) & 0xffffu);
            }
        }
        // issue tile1: rp -> pA, h -> hv
        const unsigned i1 = (unsigned)((tile0 + NB) * BN) + (unsigned)c;
        pA[0] = rp[i1]; pA[1] = rp[(size_t)NNB + i1]; pA[2] = rp[2 * (size_t)NNB + i1];
        #pragma unroll
        for (int j = 0; j < 16; ++j) hv[j] = hwb[(size_t)j * NNB + i1];
    }
    LBAR();

    #pragma unroll 1
    for (int it2 = 0; it2 < ITPB; it2 += 2) {
        const int tb = tile0 + it2 * NB;
        ITER(0, pA, pB, tb)
        ITER(1, pB, pA, tb + NB)
    }

    // ---- epilogue: reduce the two column-halves, store per-block partial ----
    // lane holds A[k = kg*32 + kt*16 + q*4 + r][de = il] (il < 6 valid)
    if (g == 0 && il < 6) {
        #pragma unroll
        for (int r = 0; r < 4; ++r) {
            ared[kg * 32 + q * 4 + r][il]      = acc0[r];
            ared[kg * 32 + 16 + q * 4 + r][il] = acc1[r];
        }
    }
    __syncthreads();
    if (g == 1 && il < 6) {
        float* dst = ws + (size_t)blockIdx.x * NENT;
        #pragma unroll
        for (int r = 0; r < 4; ++r) {
            const int ka = kg * 32 + q * 4 + r;
            const int kb = ka + 16;
            dst[ka * 6 + il] = ared[ka][il] + acc0[r];
            dst[kb * 6 + il] = ared[kb][il] + acc1[r];
        }
    }
}

// K2: 24 blocks x 512. Block eb owns entries [eb*64, +64); coalesced rows; LDS reduce.
__global__ void create_As_k2(const float* __restrict__ ws, float* __restrict__ out)
{
    __shared__ float red[8][64];
    const int eb = blockIdx.x;
    const int w  = threadIdx.x >> 6;
    const int l  = threadIdx.x & 63;
    float s = 0.f;
    #pragma unroll 4
    for (int b = w; b < NB; b += 8)
        s += ws[(size_t)b * NENT + (unsigned)(eb * 64 + l)];
    red[w][l] = s;
    __syncthreads();
    if (w == 0) {
        float v = red[0][l] + red[1][l] + red[2][l] + red[3][l]
                + red[4][l] + red[5][l] + red[6][l] + red[7][l];
        const int e  = eb * 64 + l;
        const int k  = e / 6;
        const int m6 = e - k * 6;
        const int d  = (m6 < 3) ? 0 : ((m6 < 5) ? 1 : 2);
        const int e2 = (m6 < 3) ? m6 : ((m6 < 5) ? (m6 - 2) : 2);
        out[k * 9 + d * 3 + e2] = v;
        if (d != e2) out[k * 9 + e2 * 3 + d] = v;
    }
}

extern "C" void kernel_launch(void* const* d_in, const int* in_sizes, int n_in,
                              void* d_out, int out_size, void* d_ws, size_t ws_size,
                              hipStream_t stream)
{
    const float* h  = (const float*)d_in[0];
    const float* rp = (const float*)d_in[1];
    const float* W  = (const float*)d_in[2];
    float* out = (float*)d_out;
    float* ws  = (float*)d_ws;

    hipLaunchKernelGGL(create_As_k1, dim3(NB), dim3(1024), 0, stream, h, rp, W, ws);
    hipLaunchKernelGGL(create_As_k2, dim3(NENT / 64), dim3(512), 0, stream, ws, out);
}

// Round 7
// 178.948 us; speedup vs baseline: 1.0022x; 1.0022x over previous
//
#include <hip/hip_runtime.h>
#include <hip/hip_bf16.h>

#define NCH      256
#define NNB      262144
#define BN       64
#define NTILES   (NNB / BN)   // 4096
#define NB       256          // K1 grid: 1 block per CU
#define ITPB     (NTILES / NB) // 16 tiles per block
#define NENT     (NCH * 6)

typedef __bf16        bf16x8 __attribute__((ext_vector_type(8)));
typedef float         f32x4  __attribute__((ext_vector_type(4)));
typedef unsigned int  u32x4  __attribute__((ext_vector_type(4)));
typedef unsigned int  u32x2  __attribute__((ext_vector_type(2)));
typedef short         v4s    __attribute__((ext_vector_type(4)));

union FragU  { u32x4 u; bf16x8 b; };
union Frag2U { u32x2 u; v4s    s; };

__device__ __forceinline__ unsigned pk2(float lo, float hi) {
    union { __hip_bfloat162 h2; unsigned u; } cv;
    cv.h2 = __float22bfloat162_rn(make_float2(lo, hi));
    return cv.u;
}

__device__ __forceinline__ const float* uni_ptr(const float* p) {
    unsigned long long u = (unsigned long long)p;
    unsigned lo = __builtin_amdgcn_readfirstlane((unsigned)u);
    unsigned hi = __builtin_amdgcn_readfirstlane((unsigned)(u >> 32));
    return (const float*)(((unsigned long long)hi << 32) | lo);
}

// raw barrier: LDS writes visible, global loads stay in flight (no vmcnt drain)
#define LBAR() do {                                                  \
    asm volatile("s_waitcnt lgkmcnt(0)" ::: "memory");               \
    __builtin_amdgcn_sched_barrier(0);                               \
    __builtin_amdgcn_s_barrier();                                    \
    __builtin_amdgcn_sched_barrier(0);                               \
} while (0)

// One iteration: compute tile from buf P; prepare tile+NB into buf P^1.
// Wave (g = wave&1, kg = wave>>1): k in [kg*32,+32), cols [g*32,+32).
#define ITER(P, CUR, NXT, TILE_EXPR)                                               \
{                                                                                  \
    const int tile = (TILE_EXPR);                                                  \
    const int tn1  = tile + NB;                                                    \
    const int tn2  = tile + 2 * NB;                                                \
    {   /* issue rp(tn2) -> NXT (consumed next iteration's A) */                   \
        const int lt = (tn2 < NTILES) ? tn2 : tile;                                \
        const unsigned ii = (unsigned)(lt * BN) + (unsigned)c;                     \
        NXT[0] = rp[ii];                                                           \
        NXT[1] = rp[(size_t)NNB + ii];                                             \
        NXT[2] = rp[2 * (size_t)NNB + ii];                                         \
    }                                                                              \
    __builtin_amdgcn_sched_barrier(0);                                             \
    /* ---- B: compute from htile[P], dtab[P], gT[P] ---- */                       \
    _Pragma("unroll")                                                              \
    for (int cb = 0; cb < 2; ++cb) {                                               \
        const int colb = g * 32 + cb * 16;                                         \
        Frag2U gf;                                                                 \
        gf.u = *(const u32x2*)((const char*)gT[P] +                                \
               (((unsigned)(il * 128 + (colb + q * 4) * 2)) ^                      \
                (((unsigned)(il & 7)) << 3)));                                     \
        f32x4 hp0 = {0.f, 0.f, 0.f, 0.f}, hp1 = {0.f, 0.f, 0.f, 0.f};              \
        const unsigned rb = (unsigned)((colb + il) * 512);                         \
        const unsigned sw = ((unsigned)(il & 7)) << 4;                             \
        _Pragma("unroll")                                                          \
        for (int jb = 0; jb < 8; ++jb) {                                           \
            FragU f0;                                                              \
            f0.u = *(const u32x4*)((const char*)htile[P] +                         \
                   ((rb + (unsigned)(jb * 64 + q * 16)) ^ sw));                    \
            hp0 = __builtin_amdgcn_mfma_f32_16x16x32_bf16(f0.b, wf[0][jb].b, hp0, 0, 0, 0); \
            hp1 = __builtin_amdgcn_mfma_f32_16x16x32_bf16(f0.b, wf[1][jb].b, hp1, 0, 0, 0); \
        }                                                                          \
        f32x4 d4 = *(const f32x4*)&dtab[P][0][colb + q * 4];                       \
        f32x4 i4 = *(const f32x4*)&dtab[P][1][colb + q * 4];                       \
        Frag2U a0, a1;                                                             \
        {                                                                          \
            float m0 = __sinf(fk0 * d4[0]) * i4[0] * hp0[0];                       \
            float m1 = __sinf(fk0 * d4[1]) * i4[1] * hp0[1];                       \
            float m2 = __sinf(fk0 * d4[2]) * i4[2] * hp0[2];                       \
            float m3 = __sinf(fk0 * d4[3]) * i4[3] * hp0[3];                       \
            a0.u[0] = pk2(m0, m1); a0.u[1] = pk2(m2, m3);                          \
            float n0 = __sinf(fk1 * d4[0]) * i4[0] * hp1[0];                       \
            float n1 = __sinf(fk1 * d4[1]) * i4[1] * hp1[1];                       \
            float n2 = __sinf(fk1 * d4[2]) * i4[2] * hp1[2];                       \
            float n3 = __sinf(fk1 * d4[3]) * i4[3] * hp1[3];                       \
            a1.u[0] = pk2(n0, n1); a1.u[1] = pk2(n2, n3);                          \
        }                                                                          \
        acc0 = __builtin_amdgcn_mfma_f32_16x16x16bf16_1k(a0.s, gf.s, acc0, 0, 0, 0); \
        acc1 = __builtin_amdgcn_mfma_f32_16x16x16bf16_1k(a1.s, gf.s, acc1, 0, 0, 0); \
    }                                                                              \
    __builtin_amdgcn_sched_barrier(0);                                             \
    /* ---- A: prep tile tn1 into buf P^1 (vmcnt waits land here) ---- */          \
    if (tn1 < NTILES) {                                                            \
        u32x4 w0, w1;                                                              \
        w0[0] = pk2(hv[0], hv[1]);   w0[1] = pk2(hv[2], hv[3]);                    \
        w0[2] = pk2(hv[4], hv[5]);   w0[3] = pk2(hv[6], hv[7]);                    \
        w1[0] = pk2(hv[8], hv[9]);   w1[1] = pk2(hv[10], hv[11]);                  \
        w1[2] = pk2(hv[12], hv[13]); w1[3] = pk2(hv[14], hv[15]);                  \
        const unsigned swc = ((unsigned)(c & 7)) << 4;                             \
        *(u32x4*)((char*)htile[(P) ^ 1] +                                          \
                  (((unsigned)(c * 512 + wave * 32)) ^ swc)) = w0;                 \
        *(u32x4*)((char*)htile[(P) ^ 1] +                                          \
                  (((unsigned)(c * 512 + wave * 32 + 16)) ^ swc)) = w1;            \
        float dd = sqrtf(CUR[0] * CUR[0] + CUR[1] * CUR[1] + CUR[2] * CUR[2]);     \
        float iv = 1.0f / dd;                                                      \
        if (t < 64) {                                                              \
            dtab[(P) ^ 1][0][c] = dd;                                              \
            dtab[(P) ^ 1][1][c] = iv;                                              \
            float i2 = iv * iv;                                                    \
            float gg[6] = { CUR[0] * CUR[0] * i2, CUR[0] * CUR[1] * i2,            \
                            CUR[0] * CUR[2] * i2, CUR[1] * CUR[1] * i2,            \
                            CUR[1] * CUR[2] * i2, CUR[2] * CUR[2] * i2 };          \
            _Pragma("unroll")                                                      \
            for (int de = 0; de < 6; ++de) {                                       \
                unsigned off = ((unsigned)(de * 128 + c * 2)) ^                    \
                               (((unsigned)de) << 3);                              \
                *(unsigned short*)((char*)gT[(P) ^ 1] + off) =                     \
                    (unsigned short)(pk2(gg[de], 0.f) & 0xffffu);                  \
            }                                                                      \
        }                                                                          \
        const int lt2 = (tn2 < NTILES) ? tn2 : tile;                               \
        const unsigned ii2 = (unsigned)(lt2 * BN) + (unsigned)c;                   \
        _Pragma("unroll")                                                          \
        for (int j = 0; j < 16; ++j) hv[j] = hwb[(size_t)j * NNB + ii2];           \
    }                                                                              \
    LBAR();                                                                        \
}

// K1: 1024 threads = 16 waves; wave (g,kg) owns k [kg*32,+32) x cols [g*32,+32).
// GEMM1 (swapped): hp[col][k] via mfma(h_frag, wf[kt]); GEMM2: A[k][de] via 16x16x16.
// LDS deliberately > 80 KiB (87040 B): caps occupancy at 1 block/CU (4 waves/SIMD)
// so the backend's occupancy-driven register budget is 128 VGPR, not 64 (R6: 64 VGPR
// target for 2 blocks/CU -> 69 MB spill traffic).
// ws layout: [block][entry = k*6 + m6]
__global__ __launch_bounds__(1024) void create_As_k1(
        const float* __restrict__ h, const float* __restrict__ rp,
        const float* __restrict__ W, float* __restrict__ ws)
{
    __shared__ unsigned short htile[2][BN * NCH];        // 2 x 32 KB [col][j], ^((c&7)<<4)
    __shared__ unsigned short gT[2][16 * BN];            // 2 x 2 KB [de][col], ^((de&7)<<3)
    __shared__ __align__(16) float dtab[2][2][BN];       // [p][{d,invd}][col]
    __shared__ float ared[NCH][16];                      // cross-half reduce, 16 KB (LDS pad)

    const int t    = threadIdx.x;
    const int wave = t >> 6;        // 0..15
    const int il   = t & 15;
    const int q    = (t >> 4) & 3;
    const int c    = t & 63;
    const int g    = wave & 1;      // column half
    const int kg   = wave >> 1;     // k group of 32
    const float fk0 = (float)(kg * 32 + il + 1);
    const float fk1 = fk0 + 16.0f;

    ((unsigned*)gT)[t] = 0u;        // 1024 u32 == sizeof(gT)/4: rows 6..15 stay zero

    // W fragments: lane holds W[kg*32 + kt*16 + il][jb*32 + q*8 + e]  (64 VGPR)
    FragU wf[2][8];
    #pragma unroll
    for (int kt = 0; kt < 2; ++kt) {
        const float* wr = W + (size_t)(kg * 32 + kt * 16 + il) * NCH + q * 8;
        #pragma unroll
        for (int jb = 0; jb < 8; ++jb) {
            f32x4 a = *(const f32x4*)(wr + jb * 32);
            f32x4 b = *(const f32x4*)(wr + jb * 32 + 4);
            wf[kt][jb].u[0] = pk2(a[0], a[1]);
            wf[kt][jb].u[1] = pk2(a[2], a[3]);
            wf[kt][jb].u[2] = pk2(b[0], b[1]);
            wf[kt][jb].u[3] = pk2(b[2], b[3]);
        }
    }

    f32x4 acc0 = {0.f, 0.f, 0.f, 0.f};
    f32x4 acc1 = {0.f, 0.f, 0.f, 0.f};

    const float* hwb = uni_ptr(h + (size_t)(wave * 16) * NNB);  // staging rows, by wave id

    float hv[16];
    float pA[3], pB[3];

    const int tile0 = blockIdx.x;

    __syncthreads();   // gT zero-init + wf reads done before prologue LDS writes

    // -------- prologue: stage tile0 into buf 0; issue tile1 loads --------
    {
        const unsigned ii = (unsigned)(tile0 * BN) + (unsigned)c;
        pB[0] = rp[ii]; pB[1] = rp[(size_t)NNB + ii]; pB[2] = rp[2 * (size_t)NNB + ii];
        #pragma unroll
        for (int j = 0; j < 16; ++j) hv[j] = hwb[(size_t)j * NNB + ii];

        u32x4 w0, w1;
        w0[0] = pk2(hv[0], hv[1]);   w0[1] = pk2(hv[2], hv[3]);
        w0[2] = pk2(hv[4], hv[5]);   w0[3] = pk2(hv[6], hv[7]);
        w1[0] = pk2(hv[8], hv[9]);   w1[1] = pk2(hv[10], hv[11]);
        w1[2] = pk2(hv[12], hv[13]); w1[3] = pk2(hv[14], hv[15]);
        const unsigned swc = ((unsigned)(c & 7)) << 4;
        *(u32x4*)((char*)htile[0] + (((unsigned)(c * 512 + wave * 32)) ^ swc)) = w0;
        *(u32x4*)((char*)htile[0] + (((unsigned)(c * 512 + wave * 32 + 16)) ^ swc)) = w1;

        float dd = sqrtf(pB[0] * pB[0] + pB[1] * pB[1] + pB[2] * pB[2]);
        float iv = 1.0f / dd;
        if (t < 64) {
            dtab[0][0][c] = dd; dtab[0][1][c] = iv;
            float i2 = iv * iv;
            float gg[6] = { pB[0] * pB[0] * i2, pB[0] * pB[1] * i2, pB[0] * pB[2] * i2,
                            pB[1] * pB[1] * i2, pB[1] * pB[2] * i2, pB[2] * pB[2] * i2 };
            #pragma unroll
            for (int de = 0; de < 6; ++de) {
                unsigned off = ((unsigned)(de * 128 + c * 2)) ^ (((unsigned)de) << 3);
                *(unsigned short*)((char*)gT[0] + off) =
                    (unsigned short)(pk2(gg[de], 0.f) & 0xffffu);
            }
        }
        // issue tile1: rp -> pA, h -> hv
        const unsigned i1 = (unsigned)((tile0 + NB) * BN) + (unsigned)c;
        pA[0] = rp[i1]; pA[1] = rp[(size_t)NNB + i1]; pA[2] = rp[2 * (size_t)NNB + i1];
        #pragma unroll
        for (int j = 0; j < 16; ++j) hv[j] = hwb[(size_t)j * NNB + i1];
    }
    LBAR();

    #pragma unroll 1
    for (int it2 = 0; it2 < ITPB; it2 += 2) {
        const int tb = tile0 + it2 * NB;
        ITER(0, pA, pB, tb)
        ITER(1, pB, pA, tb + NB)
    }

    // ---- epilogue: reduce the two column-halves, store per-block partial ----
    // lane holds A[k = kg*32 + kt*16 + q*4 + r][de = il] (il < 6 valid)
    if (g == 0 && il < 6) {
        #pragma unroll
        for (int r = 0; r < 4; ++r) {
            ared[kg * 32 + q * 4 + r][il]      = acc0[r];
            ared[kg * 32 + 16 + q * 4 + r][il] = acc1[r];
        }
    }
    __syncthreads();
    if (g == 1 && il < 6) {
        float* dst = ws + (size_t)blockIdx.x * NENT;
        #pragma unroll
        for (int r = 0; r < 4; ++r) {
            const int ka = kg * 32 + q * 4 + r;
            const int kb = ka + 16;
            dst[ka * 6 + il] = ared[ka][il] + acc0[r];
            dst[kb * 6 + il] = ared[kb][il] + acc1[r];
        }
    }
}

// K2: 24 blocks x 512. Block eb owns entries [eb*64, +64); coalesced rows; LDS reduce.
__global__ void create_As_k2(const float* __restrict__ ws, float* __restrict__ out)
{
    __shared__ float red[8][64];
    const int eb = blockIdx.x;
    const int w  = threadIdx.x >> 6;
    const int l  = threadIdx.x & 63;
    float s = 0.f;
    #pragma unroll 4
    for (int b = w; b < NB; b += 8)
        s += ws[(size_t)b * NENT + (unsigned)(eb * 64 + l)];
    red[w][l] = s;
    __syncthreads();
    if (w == 0) {
        float v = red[0][l] + red[1][l] + red[2][l] + red[3][l]
                + red[4][l] + red[5][l] + red[6][l] + red[7][l];
        const int e  = eb * 64 + l;
        const int k  = e / 6;
        const int m6 = e - k * 6;
        const int d  = (m6 < 3) ? 0 : ((m6 < 5) ? 1 : 2);
        const int e2 = (m6 < 3) ? m6 : ((m6 < 5) ? (m6 - 2) : 2);
        out[k * 9 + d * 3 + e2] = v;
        if (d != e2) out[k * 9 + e2 * 3 + d] = v;
    }
}

extern "C" void kernel_launch(void* const* d_in, const int* in_sizes, int n_in,
                              void* d_out, int out_size, void* d_ws, size_t ws_size,
                              hipStream_t stream)
{
    const float* h  = (const float*)d_in[0];
    const float* rp = (const float*)d_in[1];
    const float* W  = (const float*)d_in[2];
    float* out = (float*)d_out;
    float* ws  = (float*)d_ws;

    hipLaunchKernelGGL(create_As_k1, dim3(NB), dim3(1024), 0, stream, h, rp, W, ws);
    hipLaunchKernelGGL(create_As_k2, dim3(NENT / 64), dim3(512), 0, stream, ws, out);
}

// Round 8
// 84.006 us; speedup vs baseline: 2.1348x; 2.1302x over previous
//
#include <hip/hip_runtime.h>
#include <hip/hip_bf16.h>

#define NCH      256
#define NNB      262144
#define BN       64
#define NTILES   (NNB / BN)   // 4096
#define NB       512          // K1 grid: 2 blocks per CU
#define ITPB     (NTILES / NB) // 8 tiles per block
#define NENT     (NCH * 6)
#define NTHREADS 512

typedef __bf16        bf16x8 __attribute__((ext_vector_type(8)));
typedef float         f32x4  __attribute__((ext_vector_type(4)));
typedef unsigned int  u32x4  __attribute__((ext_vector_type(4)));
typedef unsigned int  u32x2  __attribute__((ext_vector_type(2)));
typedef short         v4s    __attribute__((ext_vector_type(4)));

union FragU  { u32x4 u; bf16x8 b; };
union Frag2U { u32x2 u; v4s    s; };

__device__ __forceinline__ unsigned pk2(float lo, float hi) {
    union { __hip_bfloat162 h2; unsigned u; } cv;
    cv.h2 = __float22bfloat162_rn(make_float2(lo, hi));
    return cv.u;
}

__device__ __forceinline__ const float* uni_ptr(const float* p) {
    unsigned long long u = (unsigned long long)p;
    unsigned lo = __builtin_amdgcn_readfirstlane((unsigned)u);
    unsigned hi = __builtin_amdgcn_readfirstlane((unsigned)(u >> 32));
    return (const float*)(((unsigned long long)hi << 32) | lo);
}

// raw barrier: LDS writes visible, global loads stay in flight (no vmcnt drain)
#define LBAR() do {                                                  \
    asm volatile("s_waitcnt lgkmcnt(0)" ::: "memory");               \
    __builtin_amdgcn_sched_barrier(0);                               \
    __builtin_amdgcn_s_barrier();                                    \
    __builtin_amdgcn_sched_barrier(0);                               \
} while (0)

// one 16-col compute block: GEMM1 (2 MFMAs per ds_read) + radial + GEMM2
#define CBODY(CB, P)                                                               \
{                                                                                  \
    const int colb = (CB) * 16;                                                    \
    Frag2U gf;                                                                     \
    gf.u = *(const u32x2*)((const char*)gT[P] +                                    \
           (((unsigned)(il * 128 + (colb + q * 4) * 2)) ^                          \
            (((unsigned)(il & 7)) << 3)));                                         \
    f32x4 hp0 = {0.f, 0.f, 0.f, 0.f}, hp1 = {0.f, 0.f, 0.f, 0.f};                  \
    const unsigned rb = (unsigned)((colb + il) * 512);                             \
    const unsigned sw = ((unsigned)(il & 7)) << 4;                                 \
    _Pragma("unroll")                                                              \
    for (int jb = 0; jb < 8; ++jb) {                                               \
        FragU f0;                                                                  \
        f0.u = *(const u32x4*)((const char*)htile[P] +                             \
               ((rb + (unsigned)(jb * 64 + q * 16)) ^ sw));                        \
        hp0 = __builtin_amdgcn_mfma_f32_16x16x32_bf16(f0.b, wf[0][jb].b, hp0, 0, 0, 0); \
        hp1 = __builtin_amdgcn_mfma_f32_16x16x32_bf16(f0.b, wf[1][jb].b, hp1, 0, 0, 0); \
    }                                                                              \
    f32x4 d4 = *(const f32x4*)&dtab[P][0][colb + q * 4];                           \
    f32x4 i4 = *(const f32x4*)&dtab[P][1][colb + q * 4];                           \
    Frag2U a0, a1;                                                                 \
    {                                                                              \
        float m0 = __sinf(fk0 * d4[0]) * i4[0] * hp0[0];                           \
        float m1 = __sinf(fk0 * d4[1]) * i4[1] * hp0[1];                           \
        float m2 = __sinf(fk0 * d4[2]) * i4[2] * hp0[2];                           \
        float m3 = __sinf(fk0 * d4[3]) * i4[3] * hp0[3];                           \
        a0.u[0] = pk2(m0, m1); a0.u[1] = pk2(m2, m3);                              \
        float n0 = __sinf(fk1 * d4[0]) * i4[0] * hp1[0];                           \
        float n1 = __sinf(fk1 * d4[1]) * i4[1] * hp1[1];                           \
        float n2 = __sinf(fk1 * d4[2]) * i4[2] * hp1[2];                           \
        float n3 = __sinf(fk1 * d4[3]) * i4[3] * hp1[3];                           \
        a1.u[0] = pk2(n0, n1); a1.u[1] = pk2(n2, n3);                              \
    }                                                                              \
    acc0 = __builtin_amdgcn_mfma_f32_16x16x16bf16_1k(a0.s, gf.s, acc0, 0, 0, 0);   \
    acc1 = __builtin_amdgcn_mfma_f32_16x16x16bf16_1k(a1.s, gf.s, acc1, 0, 0, 0);   \
}

// One iteration: compute tile (buf P); stage tile+NB into buf P^1.
// h prefetch for tile+NB in 2 chunks of 16 rows: chunk0 covered by cb0/1,
// chunk1 covered by cb2/3. Writes target P^1, so they don't race P reads.
#define ITER(P, CUR, NXT, TILE_EXPR)                                               \
{                                                                                  \
    const int tile = (TILE_EXPR);                                                  \
    const int tn1  = tile + NB;                                                    \
    const int tn2  = tile + 2 * NB;                                                \
    const unsigned ii1 = (unsigned)(((tn1 < NTILES) ? tn1 : tile) * BN) + (unsigned)c; \
    {   /* issue rp(tn2) -> NXT */                                                 \
        const int lt = (tn2 < NTILES) ? tn2 : tile;                                \
        const unsigned ii = (unsigned)(lt * BN) + (unsigned)c;                     \
        NXT[0] = rp[ii];                                                           \
        NXT[1] = rp[(size_t)NNB + ii];                                             \
        NXT[2] = rp[2 * (size_t)NNB + ii];                                         \
    }                                                                              \
    float hA[16];                                                                  \
    if (tn1 < NTILES) {   /* issue chunk0: rows wave*32 .. +16 of tile tn1 */      \
        _Pragma("unroll")                                                          \
        for (int j = 0; j < 16; ++j) hA[j] = hwb[(size_t)j * NNB + ii1];           \
    }                                                                              \
    __builtin_amdgcn_sched_barrier(0);                                             \
    CBODY(0, P)                                                                    \
    CBODY(1, P)                                                                    \
    __builtin_amdgcn_sched_barrier(0);                                             \
    float hB[16];                                                                  \
    if (tn1 < NTILES) {                                                            \
        /* pack+write chunk0 (waits its vmcnt), then issue chunk1 */               \
        u32x4 w0, w1;                                                              \
        w0[0] = pk2(hA[0], hA[1]);   w0[1] = pk2(hA[2], hA[3]);                    \
        w0[2] = pk2(hA[4], hA[5]);   w0[3] = pk2(hA[6], hA[7]);                    \
        w1[0] = pk2(hA[8], hA[9]);   w1[1] = pk2(hA[10], hA[11]);                  \
        w1[2] = pk2(hA[12], hA[13]); w1[3] = pk2(hA[14], hA[15]);                  \
        const unsigned swc = ((unsigned)(c & 7)) << 4;                             \
        *(u32x4*)((char*)htile[(P) ^ 1] +                                          \
                  (((unsigned)(c * 512 + wave * 64)) ^ swc)) = w0;                 \
        *(u32x4*)((char*)htile[(P) ^ 1] +                                          \
                  (((unsigned)(c * 512 + wave * 64 + 16)) ^ swc)) = w1;            \
        _Pragma("unroll")                                                          \
        for (int j = 0; j < 16; ++j) hB[j] = hwb[(size_t)(16 + j) * NNB + ii1];    \
    }                                                                              \
    __builtin_amdgcn_sched_barrier(0);                                             \
    CBODY(2, P)                                                                    \
    CBODY(3, P)                                                                    \
    __builtin_amdgcn_sched_barrier(0);                                             \
    if (tn1 < NTILES) {   /* pack+write chunk1; dtab/gT for tile tn1 from CUR */   \
        u32x4 w2, w3;                                                              \
        w2[0] = pk2(hB[0], hB[1]);   w2[1] = pk2(hB[2], hB[3]);                    \
        w2[2] = pk2(hB[4], hB[5]);   w2[3] = pk2(hB[6], hB[7]);                    \
        w3[0] = pk2(hB[8], hB[9]);   w3[1] = pk2(hB[10], hB[11]);                  \
        w3[2] = pk2(hB[12], hB[13]); w3[3] = pk2(hB[14], hB[15]);                  \
        const unsigned swc = ((unsigned)(c & 7)) << 4;                             \
        *(u32x4*)((char*)htile[(P) ^ 1] +                                          \
                  (((unsigned)(c * 512 + wave * 64 + 32)) ^ swc)) = w2;            \
        *(u32x4*)((char*)htile[(P) ^ 1] +                                          \
                  (((unsigned)(c * 512 + wave * 64 + 48)) ^ swc)) = w3;            \
        float dd = sqrtf(CUR[0] * CUR[0] + CUR[1] * CUR[1] + CUR[2] * CUR[2]);     \
        float iv = 1.0f / dd;                                                      \
        if (t < 64) {                                                              \
            dtab[(P) ^ 1][0][c] = dd;                                              \
            dtab[(P) ^ 1][1][c] = iv;                                              \
            float i2 = iv * iv;                                                    \
            float gg[6] = { CUR[0] * CUR[0] * i2, CUR[0] * CUR[1] * i2,            \
                            CUR[0] * CUR[2] * i2, CUR[1] * CUR[1] * i2,            \
                            CUR[1] * CUR[2] * i2, CUR[2] * CUR[2] * i2 };          \
            _Pragma("unroll")                                                      \
            for (int de = 0; de < 6; ++de) {                                       \
                unsigned off = ((unsigned)(de * 128 + c * 2)) ^                    \
                               (((unsigned)de) << 3);                              \
                *(unsigned short*)((char*)gT[(P) ^ 1] + off) =                     \
                    (unsigned short)(pk2(gg[de], 0.f) & 0xffffu);                  \
            }                                                                      \
        }                                                                          \
    }                                                                              \
    LBAR();                                                                        \
}

// K1: 512 threads = 8 waves; wave owns k in [wave*32,+32) over all 64 cols.
// GEMM1 (swapped): hp[col][k] via mfma(h_frag, wf[kt]) — each ds_read feeds 2 MFMAs.
// GEMM2: A[k][de] via mfma 16x16x16bf16_1k against the G[col][de] table.
// __launch_bounds__(512,2): empirically yields a 128-VGPR budget
// (131072 regs/CU / 1024 threads); 1024-thread blocks got 64 and spilled (R5-R7).
// ws layout: [block][entry = k*6 + m6]
__global__ __launch_bounds__(NTHREADS, 2) void create_As_k1(
        const float* __restrict__ h, const float* __restrict__ rp,
        const float* __restrict__ W, float* __restrict__ ws)
{
    __shared__ unsigned short htile[2][BN * NCH];        // 2 x 32 KB [col][j], ^((c&7)<<4)
    __shared__ unsigned short gT[2][16 * BN];            // 2 x 2 KB [de][col], ^((de&7)<<3)
    __shared__ __align__(16) float dtab[2][2][BN];       // [p][{d,invd}][col]

    const int t    = threadIdx.x;
    const int wave = t >> 6;        // 0..7
    const int il   = t & 15;
    const int q    = (t >> 4) & 3;
    const int c    = t & 63;
    const int k0   = wave * 32;
    const float fk0 = (float)(k0 + il + 1);
    const float fk1 = fk0 + 16.0f;

    // zero gT (rows 6..15 must stay zero); 2048 u32 total, 512 threads
    #pragma unroll
    for (int z = 0; z < 4; ++z) ((unsigned*)gT)[t + z * NTHREADS] = 0u;

    // W fragments: lane holds W[k0 + kt*16 + il][jb*32 + q*8 + e]  (64 VGPR)
    FragU wf[2][8];
    #pragma unroll
    for (int kt = 0; kt < 2; ++kt) {
        const float* wr = W + (size_t)(k0 + kt * 16 + il) * NCH + q * 8;
        #pragma unroll
        for (int jb = 0; jb < 8; ++jb) {
            f32x4 a = *(const f32x4*)(wr + jb * 32);
            f32x4 b = *(const f32x4*)(wr + jb * 32 + 4);
            wf[kt][jb].u[0] = pk2(a[0], a[1]);
            wf[kt][jb].u[1] = pk2(a[2], a[3]);
            wf[kt][jb].u[2] = pk2(b[0], b[1]);
            wf[kt][jb].u[3] = pk2(b[2], b[3]);
        }
    }

    f32x4 acc0 = {0.f, 0.f, 0.f, 0.f};
    f32x4 acc1 = {0.f, 0.f, 0.f, 0.f};

    // staging rows: wave stages rows [wave*32, +32) of the tile
    const float* hwb = uni_ptr(h + (size_t)(wave * 32) * NNB);

    float pA[3], pB[3];
    const int tile0 = blockIdx.x;

    __syncthreads();   // gT zero-init + any LDS reuse ordering before prologue writes

    // -------- prologue: stage tile0 into buf 0; issue rp(tile1) --------
    {
        const unsigned ii = (unsigned)(tile0 * BN) + (unsigned)c;
        pB[0] = rp[ii]; pB[1] = rp[(size_t)NNB + ii]; pB[2] = rp[2 * (size_t)NNB + ii];
        float hv[32];
        #pragma unroll
        for (int j = 0; j < 32; ++j) hv[j] = hwb[(size_t)j * NNB + ii];

        const unsigned swc = ((unsigned)(c & 7)) << 4;
        #pragma unroll
        for (int g2 = 0; g2 < 4; ++g2) {
            u32x4 w0;
            w0[0] = pk2(hv[g2 * 8 + 0], hv[g2 * 8 + 1]);
            w0[1] = pk2(hv[g2 * 8 + 2], hv[g2 * 8 + 3]);
            w0[2] = pk2(hv[g2 * 8 + 4], hv[g2 * 8 + 5]);
            w0[3] = pk2(hv[g2 * 8 + 6], hv[g2 * 8 + 7]);
            *(u32x4*)((char*)htile[0] +
                      (((unsigned)(c * 512 + wave * 64 + g2 * 16)) ^ swc)) = w0;
        }

        float dd = sqrtf(pB[0] * pB[0] + pB[1] * pB[1] + pB[2] * pB[2]);
        float iv = 1.0f / dd;
        if (t < 64) {
            dtab[0][0][c] = dd; dtab[0][1][c] = iv;
            float i2 = iv * iv;
            float gg[6] = { pB[0] * pB[0] * i2, pB[0] * pB[1] * i2, pB[0] * pB[2] * i2,
                            pB[1] * pB[1] * i2, pB[1] * pB[2] * i2, pB[2] * pB[2] * i2 };
            #pragma unroll
            for (int de = 0; de < 6; ++de) {
                unsigned off = ((unsigned)(de * 128 + c * 2)) ^ (((unsigned)de) << 3);
                *(unsigned short*)((char*)gT[0] + off) =
                    (unsigned short)(pk2(gg[de], 0.f) & 0xffffu);
            }
        }
        // issue rp(tile1) -> pA  (h for tile1 is issued inside iteration 0)
        const unsigned i1 = (unsigned)((tile0 + NB) * BN) + (unsigned)c;
        pA[0] = rp[i1]; pA[1] = rp[(size_t)NNB + i1]; pA[2] = rp[2 * (size_t)NNB + i1];
    }
    LBAR();

    #pragma unroll 1
    for (int it2 = 0; it2 < ITPB; it2 += 2) {
        const int tb = tile0 + it2 * NB;
        ITER(0, pA, pB, tb)
        ITER(1, pB, pA, tb + NB)
    }

    // ---- store: lane holds A[k = k0 + q*4 + r (+16)][de = il] ----
    if (il < 6) {
        float* dst = ws + (size_t)blockIdx.x * NENT;
        #pragma unroll
        for (int r = 0; r < 4; ++r) {
            dst[(k0 + q * 4 + r) * 6 + il]      = acc0[r];
            dst[(k0 + 16 + q * 4 + r) * 6 + il] = acc1[r];
        }
    }
}

// K2: 24 blocks x 512. Block eb owns entries [eb*64, +64); coalesced rows; LDS reduce.
__global__ void create_As_k2(const float* __restrict__ ws, float* __restrict__ out)
{
    __shared__ float red[8][64];
    const int eb = blockIdx.x;
    const int w  = threadIdx.x >> 6;
    const int l  = threadIdx.x & 63;
    float s = 0.f;
    #pragma unroll 4
    for (int b = w; b < NB; b += 8)
        s += ws[(size_t)b * NENT + (unsigned)(eb * 64 + l)];
    red[w][l] = s;
    __syncthreads();
    if (w == 0) {
        float v = red[0][l] + red[1][l] + red[2][l] + red[3][l]
                + red[4][l] + red[5][l] + red[6][l] + red[7][l];
        const int e  = eb * 64 + l;
        const int k  = e / 6;
        const int m6 = e - k * 6;
        const int d  = (m6 < 3) ? 0 : ((m6 < 5) ? 1 : 2);
        const int e2 = (m6 < 3) ? m6 : ((m6 < 5) ? (m6 - 2) : 2);
        out[k * 9 + d * 3 + e2] = v;
        if (d != e2) out[k * 9 + e2 * 3 + d] = v;
    }
}

extern "C" void kernel_launch(void* const* d_in, const int* in_sizes, int n_in,
                              void* d_out, int out_size, void* d_ws, size_t ws_size,
                              hipStream_t stream)
{
    const float* h  = (const float*)d_in[0];
    const float* rp = (const float*)d_in[1];
    const float* W  = (const float*)d_in[2];
    float* out = (float*)d_out;
    float* ws  = (float*)d_ws;

    hipLaunchKernelGGL(create_As_k1, dim3(NB), dim3(NTHREADS), 0, stream, h, rp, W, ws);
    hipLaunchKernelGGL(create_As_k2, dim3(NENT / 64), dim3(512), 0, stream, ws, out);
}